// Round 16
// baseline (3943.182 us; speedup 1.0000x reference)
//
#include <hip/hip_runtime.h>
#include <math.h>

#define M0 131072
#define NC 4096
#define FDIM 324   // 6*54

// ---- batched asm LDS ops, wait INSIDE each block (proven-correct R12/R15 form)
#define DSWIN21(w0, w1, w2, w3, w4, g, addr)                                   \
  asm volatile("ds_read2_b64 %0, %6 offset0:0 offset1:1\n\t"                   \
               "ds_read2_b64 %1, %6 offset0:2 offset1:3\n\t"                   \
               "ds_read2_b64 %2, %6 offset0:4 offset1:5\n\t"                   \
               "ds_read2_b64 %3, %6 offset0:6 offset1:7\n\t"                   \
               "ds_read2_b64 %4, %6 offset0:8 offset1:9\n\t"                   \
               "ds_read_b32 %5, %6 offset:80\n\t"                              \
               "s_waitcnt lgkmcnt(0)"                                          \
               : "=v"(w0), "=v"(w1), "=v"(w2), "=v"(w3), "=v"(w4), "=v"(g)     \
               : "v"(addr))

#define DSWIN24(w0, w1, w2, w3, w4, w5, addr)                                  \
  asm volatile("ds_read_b128 %0, %6 offset:0\n\t"                              \
               "ds_read_b128 %1, %6 offset:16\n\t"                             \
               "ds_read_b128 %2, %6 offset:32\n\t"                             \
               "ds_read_b128 %3, %6 offset:48\n\t"                             \
               "ds_read_b128 %4, %6 offset:64\n\t"                             \
               "ds_read_b128 %5, %6 offset:80\n\t"                             \
               "s_waitcnt lgkmcnt(0)"                                          \
               : "=v"(w0), "=v"(w1), "=v"(w2), "=v"(w3), "=v"(w4), "=v"(w5)    \
               : "v"(addr))

#define DSWQ5(q, addr)                                                         \
  asm volatile("ds_read_b128 %0, %5 offset:0\n\t"                              \
               "ds_read_b128 %1, %5 offset:16\n\t"                             \
               "ds_read_b128 %2, %5 offset:32\n\t"                             \
               "ds_read_b128 %3, %5 offset:48\n\t"                             \
               "ds_read_b128 %4, %5 offset:64\n\t"                             \
               "s_waitcnt lgkmcnt(0)"                                          \
               : "=v"(q[0]), "=v"(q[1]), "=v"(q[2]), "=v"(q[3]), "=v"(q[4])    \
               : "v"(addr))

#define DSW64(addr, val)  asm volatile("ds_write_b64 %0, %1" :: "v"(addr), "v"(val))
#define DSW32(addr, val)  asm volatile("ds_write_b32 %0, %1" :: "v"(addr), "v"(val))

// ---- compile-time window element accessors ----
template<int J>
__device__ __forceinline__ float el21(const float4 (&W)[5], float g) {
    if constexpr (J >= 20) return g;
    else {
        constexpr int q = J >> 2, r = J & 3;
        if constexpr (r == 0) return W[q].x;
        else if constexpr (r == 1) return W[q].y;
        else if constexpr (r == 2) return W[q].z;
        else return W[q].w;
    }
}
template<int J>
__device__ __forceinline__ float el24(const float4 (&W)[6]) {
    constexpr int q = J >> 2, r = J & 3;
    if constexpr (r == 0) return W[q].x;
    else if constexpr (r == 1) return W[q].y;
    else if constexpr (r == 2) return W[q].z;
    else return W[q].w;
}

template<int K0>
__device__ __forceinline__ void fq2(const float4 wq, const float4 (&W)[5], float g,
                                    float& a0, float& a1) {
    a0 = fmaf(el21<K0 + 0>(W, g), wq.x, a0); a1 = fmaf(el21<K0 + 1>(W, g), wq.x, a1);
    a0 = fmaf(el21<K0 + 1>(W, g), wq.y, a0); a1 = fmaf(el21<K0 + 2>(W, g), wq.y, a1);
    a0 = fmaf(el21<K0 + 2>(W, g), wq.z, a0); a1 = fmaf(el21<K0 + 3>(W, g), wq.z, a1);
    a0 = fmaf(el21<K0 + 3>(W, g), wq.w, a0); a1 = fmaf(el21<K0 + 4>(W, g), wq.w, a1);
}
template<int K0>
__device__ __forceinline__ void fq4(const float4 wq, const float4 (&W)[6], float (&a)[4]) {
    a[0] = fmaf(el24<K0 + 0>(W), wq.x, a[0]); a[1] = fmaf(el24<K0 + 1>(W), wq.x, a[1]);
    a[2] = fmaf(el24<K0 + 2>(W), wq.x, a[2]); a[3] = fmaf(el24<K0 + 3>(W), wq.x, a[3]);
    a[0] = fmaf(el24<K0 + 1>(W), wq.y, a[0]); a[1] = fmaf(el24<K0 + 2>(W), wq.y, a[1]);
    a[2] = fmaf(el24<K0 + 3>(W), wq.y, a[2]); a[3] = fmaf(el24<K0 + 4>(W), wq.y, a[3]);
    a[0] = fmaf(el24<K0 + 2>(W), wq.z, a[0]); a[1] = fmaf(el24<K0 + 3>(W), wq.z, a[1]);
    a[2] = fmaf(el24<K0 + 4>(W), wq.z, a[2]); a[3] = fmaf(el24<K0 + 5>(W), wq.z, a[3]);
    a[0] = fmaf(el24<K0 + 3>(W), wq.w, a[0]); a[1] = fmaf(el24<K0 + 4>(W), wq.w, a[1]);
    a[2] = fmaf(el24<K0 + 5>(W), wq.w, a[2]); a[3] = fmaf(el24<K0 + 6>(W), wq.w, a[3]);
}

#define FQ2ALL(Q, W, g, a0, a1)                                                \
  do { fq2<0>(Q[0], W, g, a0, a1);  fq2<4>(Q[1], W, g, a0, a1);                \
       fq2<8>(Q[2], W, g, a0, a1);  fq2<12>(Q[3], W, g, a0, a1);               \
       fq2<16>(Q[4], W, g, a0, a1); } while (0)

// -------- Kernel 1: paired-atom conv pipeline + register segment accumulation --
// Each wave: 4 atoms as 2 pairs; weights read from LDS ONCE per pair (not per
// atom) -> DS-pipe traffic ~95 instr/atom vs 161 (R15 was DS-pipe-bound).
__global__ __launch_bounds__(256, 4) void atom_kernel(
    const float* __restrict__ oh_g,    // [M0,92]
    const float* __restrict__ env_g,   // [M0,55]
    const int*   __restrict__ idx_g,   // [M0] sorted
    const float* __restrict__ wA, const float* __restrict__ bA,  // [3*20],[3]
    const float* __restrict__ w1, const float* __restrict__ b1,  // [3*20],[3]
    const float* __restrict__ w2, const float* __restrict__ b2,  // [6*3*20],[6]
    float* __restrict__ sums,          // [NC,324]
    float* __restrict__ counts)        // [NC]
{
    __shared__ __align__(16) float w_lds[480];          // wA[0:60] w1[60:120] w2[120:480]
    __shared__ __align__(16) float s_total[4][2][280];  // per wave, per pair-slot
    __shared__ __align__(16) float s_one1[4][2][384];   // [3][128]; first 92 = oh scratch

    // XCD-chunk swizzle: consecutive (same-crystal) blocks share one XCD L2.
    const int bid = (blockIdx.x & 7) * 1024 + (blockIdx.x >> 3);

    const int wave = threadIdx.x >> 6;
    const int lane = threadIdx.x & 63;
    const int tid  = threadIdx.x;

    const unsigned w_b   = (unsigned)(size_t)w_lds;
    const unsigned wD_b  = w_b + 480u;                  // w2 bytes
    const unsigned totA_b = (unsigned)(size_t)&s_total[wave][0][0];
    const unsigned totB_b = (unsigned)(size_t)&s_total[wave][1][0];
    const unsigned oneA_b = (unsigned)(size_t)&s_one1[wave][0][0];
    const unsigned oneB_b = (unsigned)(size_t)&s_one1[wave][1][0];
    const unsigned lane8  = (unsigned)lane * 8u;
    const unsigned lane16 = (unsigned)lane * 16u;

    // ---- stage all conv weights into LDS once per block ----
    for (int i = tid; i < 360; i += 256) DSW32(w_b + (120u + (unsigned)i) * 4u, w2[i]);
    if (tid < 60)       DSW32(w_b + (unsigned)tid * 4u, wA[tid]);
    else if (tid < 120) DSW32(w_b + (unsigned)tid * 4u, w1[tid - 60]);
    __syncthreads();

    const int wbase = bid * 16 + wave * 4;

    float fa[6] = {0.f, 0.f, 0.f, 0.f, 0.f, 0.f};
    float cnt = 0.f;
    int cur = idx_g[wbase];

#define FLUSH()                                                                \
    do {                                                                       \
        if (lane < 54) {                                                       \
            float* dst = sums + (size_t)cur * FDIM + lane;                     \
            _Pragma("unroll")                                                  \
            for (int c2 = 0; c2 < 6; ++c2) {                                   \
                atomicAdd(dst + c2 * 54, fa[c2]);                              \
                fa[c2] = 0.f;                                                  \
            }                                                                  \
        }                                                                      \
        if (lane == 0) atomicAdd(&counts[cur], cnt);                           \
        cnt = 0.f;                                                             \
    } while (0)

    #pragma unroll
    for (int pp = 0; pp < 2; ++pp) {
        const int aA = wbase + 2 * pp;
        const int aB = aA + 1;
        const int cryA = idx_g[aA];
        const int cryB = idx_g[aB];

        // ---- Phase A: both atoms' one-hot (92) + env (55) into LDS ----
        if (lane < 46) {
            const float2 vA = *reinterpret_cast<const float2*>(oh_g + (size_t)aA * 92 + 2 * lane);
            const float2 vB = *reinterpret_cast<const float2*>(oh_g + (size_t)aB * 92 + 2 * lane);
            DSW64(oneA_b + lane8, vA);
            DSW64(oneB_b + lane8, vB);
        }
        if (lane < 55) {
            DSW32(totA_b + (219u + (unsigned)lane) * 4u, env_g[(size_t)aA * 55 + lane]);
            DSW32(totB_b + (219u + (unsigned)lane) * 4u, env_g[(size_t)aB * 55 + lane]);
        }

        // ---- Phase B: conva weights ONCE, applied to both atoms ----
        {
            float4 q0[5], q1[5], q2[5];
            DSWQ5(q0, w_b);
            DSWQ5(q1, w_b + 80u);
            DSWQ5(q2, w_b + 160u);
            if (lane < 37) {
                const unsigned p2 = 2u * (unsigned)lane;
                #pragma unroll
                for (int s = 0; s < 2; ++s) {
                    const unsigned ohb  = s ? oneB_b : oneA_b;
                    const unsigned totb = s ? totB_b : totA_b;
                    float4 W[5]; float g;
                    DSWIN21(W[0], W[1], W[2], W[3], W[4], g, ohb + lane8);
                    float a0 = bA[0], a1 = a0;
                    FQ2ALL(q0, W, g, a0, a1);
                    DSW32(totb + p2 * 4u, fmaxf(a0, 0.f));
                    if (p2 + 1 < 73) DSW32(totb + (p2 + 1) * 4u, fmaxf(a1, 0.f));
                    a0 = bA[1]; a1 = a0;
                    FQ2ALL(q1, W, g, a0, a1);
                    DSW32(totb + (73u + p2) * 4u, fmaxf(a0, 0.f));
                    if (p2 + 1 < 73) DSW32(totb + (74u + p2) * 4u, fmaxf(a1, 0.f));
                    a0 = bA[2]; a1 = a0;
                    FQ2ALL(q2, W, g, a0, a1);
                    DSW32(totb + (146u + p2) * 4u, fmaxf(a0, 0.f));
                    if (p2 + 1 < 73) DSW32(totb + (147u + p2) * 4u, fmaxf(a1, 0.f));
                }
            }
        }

        // ---- Phase C: conv1 weights ONCE, both atoms (64 lanes x 4 pos) ----
        {
            float4 q0[5], q1[5], q2[5];
            DSWQ5(q0, w_b + 240u);
            DSWQ5(q1, w_b + 320u);
            DSWQ5(q2, w_b + 400u);
            #pragma unroll
            for (int s = 0; s < 2; ++s) {
                const unsigned totb = s ? totB_b : totA_b;
                const unsigned oneb = s ? oneB_b : oneA_b;
                float4 W[6];
                DSWIN24(W[0], W[1], W[2], W[3], W[4], W[5], totb + lane16);
                float a4[4] = {b1[0], b1[0], b1[0], b1[0]};
                fq4<0>(q0[0], W, a4); fq4<4>(q0[1], W, a4); fq4<8>(q0[2], W, a4);
                fq4<12>(q0[3], W, a4); fq4<16>(q0[4], W, a4);
                float2 st;
                st.x = fmaxf(fmaxf(a4[0], a4[1]), 0.f);
                st.y = fmaxf(fmaxf(a4[2], a4[3]), 0.f);
                DSW64(oneb + (2u * (unsigned)lane) * 4u, st);
                float b4[4] = {b1[1], b1[1], b1[1], b1[1]};
                fq4<0>(q1[0], W, b4); fq4<4>(q1[1], W, b4); fq4<8>(q1[2], W, b4);
                fq4<12>(q1[3], W, b4); fq4<16>(q1[4], W, b4);
                st.x = fmaxf(fmaxf(b4[0], b4[1]), 0.f);
                st.y = fmaxf(fmaxf(b4[2], b4[3]), 0.f);
                DSW64(oneb + (128u + 2u * (unsigned)lane) * 4u, st);
                float c4[4] = {b1[2], b1[2], b1[2], b1[2]};
                fq4<0>(q2[0], W, c4); fq4<4>(q2[1], W, c4); fq4<8>(q2[2], W, c4);
                fq4<12>(q2[3], W, c4); fq4<16>(q2[4], W, c4);
                st.x = fmaxf(fmaxf(c4[0], c4[1]), 0.f);
                st.y = fmaxf(fmaxf(c4[2], c4[3]), 0.f);
                DSW64(oneb + (256u + 2u * (unsigned)lane) * 4u, st);
            }
        }

        // ---- Phase D: conv2 weights ONCE per (ch,c2), both atoms' windows ----
        float accA0[6], accA1[6], accB0[6], accB1[6];
        #pragma unroll
        for (int c2 = 0; c2 < 6; ++c2) {
            accA0[c2] = b2[c2]; accA1[c2] = accA0[c2];
            accB0[c2] = accA0[c2]; accB1[c2] = accA0[c2];
        }
        #pragma unroll
        for (int ch = 0; ch < 3; ++ch) {
            float4 Wa[5]; float ga;
            float4 Wb[5]; float gb;
            DSWIN21(Wa[0], Wa[1], Wa[2], Wa[3], Wa[4], ga,
                    oneA_b + (unsigned)ch * 512u + lane8);
            DSWIN21(Wb[0], Wb[1], Wb[2], Wb[3], Wb[4], gb,
                    oneB_b + (unsigned)ch * 512u + lane8);
            #pragma unroll
            for (int c2 = 0; c2 < 6; ++c2) {
                float4 wq[5];
                DSWQ5(wq, wD_b + ((unsigned)c2 * 3u + (unsigned)ch) * 80u);
                FQ2ALL(wq, Wa, ga, accA0[c2], accA1[c2]);
                FQ2ALL(wq, Wb, gb, accB0[c2], accB1[c2]);
            }
        }

        // ---- accumulate per atom with crystal-change flush ----
        if (cryA != cur) { FLUSH(); cur = cryA; }
        if (lane < 54) {
            #pragma unroll
            for (int c2 = 0; c2 < 6; ++c2)
                fa[c2] += fmaxf(fmaxf(accA0[c2], accA1[c2]), 0.f);
        }
        cnt += 1.f;
        if (cryB != cur) { FLUSH(); cur = cryB; }
        if (lane < 54) {
            #pragma unroll
            for (int c2 = 0; c2 < 6; ++c2)
                fa[c2] += fmaxf(fmaxf(accB0[c2], accB1[c2]), 0.f);
        }
        cnt += 1.f;
    }

    FLUSH();
#undef FLUSH
}

// -------- Kernel 2: per-crystal mean+relu, 324->32 softplus, 32->1 ----------
__global__ __launch_bounds__(64) void head_kernel(
    const float* __restrict__ sums, const float* __restrict__ counts,
    const float* __restrict__ lin_w, const float* __restrict__ lin_b,
    const float* __restrict__ lin1_w, const float* __restrict__ lin1_b,
    float* __restrict__ out)
{
    __shared__ float p[FDIM];
    const int c = blockIdx.x;
    const int lane = threadIdx.x;
    const float inv = 1.0f / fmaxf(counts[c], 1.0f);
    for (int i = lane; i < FDIM; i += 64)
        p[i] = fmaxf(sums[(size_t)c * FDIM + i] * inv, 0.f);
    __syncthreads();

    float r = 0.f;
    if (lane < 32) {
        float acc = lin_b[lane];
        const float* wrow = lin_w + lane * FDIM;
        #pragma unroll 4
        for (int i = 0; i < FDIM; ++i) acc = fmaf(p[i], wrow[i], acc);
        const float sp = (acc > 0.f) ? acc + log1pf(expf(-acc)) : log1pf(expf(acc));
        r = sp * lin1_w[lane];
    }
    #pragma unroll
    for (int off = 16; off; off >>= 1) r += __shfl_down(r, off);
    if (lane == 0) out[c] = r + lin1_b[0];
}

extern "C" void kernel_launch(void* const* d_in, const int* in_sizes, int n_in,
                              void* d_out, int out_size, void* d_ws, size_t ws_size,
                              hipStream_t stream) {
    (void)in_sizes; (void)n_in; (void)out_size; (void)ws_size;
    const float* oh    = (const float*)d_in[0];
    const float* env   = (const float*)d_in[1];
    const int*   idx   = (const int*)  d_in[2];
    // d_in[3] = num_segments (constant 4096)
    const float* wA    = (const float*)d_in[4];
    const float* bA    = (const float*)d_in[5];
    const float* w1    = (const float*)d_in[6];
    const float* b1    = (const float*)d_in[7];
    const float* w2    = (const float*)d_in[8];
    const float* b2    = (const float*)d_in[9];
    const float* lin_w = (const float*)d_in[10];
    const float* lin_b = (const float*)d_in[11];
    const float* lin1_w= (const float*)d_in[12];
    const float* lin1_b= (const float*)d_in[13];

    float* sums   = (float*)d_ws;             // [NC*FDIM]
    float* counts = sums + (size_t)NC * FDIM; // [NC]

    hipMemsetAsync(d_ws, 0, ((size_t)NC * FDIM + NC) * sizeof(float), stream);

    // 8192 blocks x 4 waves x 4 atoms = M0
    atom_kernel<<<M0 / 16, 256, 0, stream>>>(oh, env, idx, wA, bA, w1, b1,
                                             w2, b2, sums, counts);
    head_kernel<<<NC, 64, 0, stream>>>(sums, counts, lin_w, lin_b, lin1_w, lin1_b,
                                       (float*)d_out);
}

// Round 18
// 3702.154 us; speedup vs baseline: 1.0651x; 1.0651x over previous
//
#include <hip/hip_runtime.h>
#include <math.h>

#define M0 131072
#define NC 4096
#define FDIM 324   // 6*54

// ---- batched asm LDS ops, wait INSIDE each block (proven-correct R12/R15 form)
#define DSWIN21(w0, w1, w2, w3, w4, g, addr)                                   \
  asm volatile("ds_read2_b64 %0, %6 offset0:0 offset1:1\n\t"                   \
               "ds_read2_b64 %1, %6 offset0:2 offset1:3\n\t"                   \
               "ds_read2_b64 %2, %6 offset0:4 offset1:5\n\t"                   \
               "ds_read2_b64 %3, %6 offset0:6 offset1:7\n\t"                   \
               "ds_read2_b64 %4, %6 offset0:8 offset1:9\n\t"                   \
               "ds_read_b32 %5, %6 offset:80\n\t"                              \
               "s_waitcnt lgkmcnt(0)"                                          \
               : "=v"(w0), "=v"(w1), "=v"(w2), "=v"(w3), "=v"(w4), "=v"(g)     \
               : "v"(addr))

#define DSWIN24(w0, w1, w2, w3, w4, w5, addr)                                  \
  asm volatile("ds_read_b128 %0, %6 offset:0\n\t"                              \
               "ds_read_b128 %1, %6 offset:16\n\t"                             \
               "ds_read_b128 %2, %6 offset:32\n\t"                             \
               "ds_read_b128 %3, %6 offset:48\n\t"                             \
               "ds_read_b128 %4, %6 offset:64\n\t"                             \
               "ds_read_b128 %5, %6 offset:80\n\t"                             \
               "s_waitcnt lgkmcnt(0)"                                          \
               : "=v"(w0), "=v"(w1), "=v"(w2), "=v"(w3), "=v"(w4), "=v"(w5)    \
               : "v"(addr))

#define DSWQ5(q, addr)                                                         \
  asm volatile("ds_read_b128 %0, %5 offset:0\n\t"                              \
               "ds_read_b128 %1, %5 offset:16\n\t"                             \
               "ds_read_b128 %2, %5 offset:32\n\t"                             \
               "ds_read_b128 %3, %5 offset:48\n\t"                             \
               "ds_read_b128 %4, %5 offset:64\n\t"                             \
               "s_waitcnt lgkmcnt(0)"                                          \
               : "=v"(q[0]), "=v"(q[1]), "=v"(q[2]), "=v"(q[3]), "=v"(q[4])    \
               : "v"(addr))

#define DSW64(addr, val)  asm volatile("ds_write_b64 %0, %1" :: "v"(addr), "v"(val))
#define DSW32(addr, val)  asm volatile("ds_write_b32 %0, %1" :: "v"(addr), "v"(val))

// ---- compile-time window element accessors ----
template<int J>
__device__ __forceinline__ float el21(const float4 (&W)[5], float g) {
    if constexpr (J >= 20) return g;
    else {
        constexpr int q = J >> 2, r = J & 3;
        if constexpr (r == 0) return W[q].x;
        else if constexpr (r == 1) return W[q].y;
        else if constexpr (r == 2) return W[q].z;
        else return W[q].w;
    }
}
template<int J>
__device__ __forceinline__ float el24(const float4 (&W)[6]) {
    constexpr int q = J >> 2, r = J & 3;
    if constexpr (r == 0) return W[q].x;
    else if constexpr (r == 1) return W[q].y;
    else if constexpr (r == 2) return W[q].z;
    else return W[q].w;
}

template<int K0>
__device__ __forceinline__ void fq2(const float4 wq, const float4 (&W)[5], float g,
                                    float& a0, float& a1) {
    a0 = fmaf(el21<K0 + 0>(W, g), wq.x, a0); a1 = fmaf(el21<K0 + 1>(W, g), wq.x, a1);
    a0 = fmaf(el21<K0 + 1>(W, g), wq.y, a0); a1 = fmaf(el21<K0 + 2>(W, g), wq.y, a1);
    a0 = fmaf(el21<K0 + 2>(W, g), wq.z, a0); a1 = fmaf(el21<K0 + 3>(W, g), wq.z, a1);
    a0 = fmaf(el21<K0 + 3>(W, g), wq.w, a0); a1 = fmaf(el21<K0 + 4>(W, g), wq.w, a1);
}
template<int K0>
__device__ __forceinline__ void fq4(const float4 wq, const float4 (&W)[6], float (&a)[4]) {
    a[0] = fmaf(el24<K0 + 0>(W), wq.x, a[0]); a[1] = fmaf(el24<K0 + 1>(W), wq.x, a[1]);
    a[2] = fmaf(el24<K0 + 2>(W), wq.x, a[2]); a[3] = fmaf(el24<K0 + 3>(W), wq.x, a[3]);
    a[0] = fmaf(el24<K0 + 1>(W), wq.y, a[0]); a[1] = fmaf(el24<K0 + 2>(W), wq.y, a[1]);
    a[2] = fmaf(el24<K0 + 3>(W), wq.y, a[2]); a[3] = fmaf(el24<K0 + 4>(W), wq.y, a[3]);
    a[0] = fmaf(el24<K0 + 2>(W), wq.z, a[0]); a[1] = fmaf(el24<K0 + 3>(W), wq.z, a[1]);
    a[2] = fmaf(el24<K0 + 4>(W), wq.z, a[2]); a[3] = fmaf(el24<K0 + 5>(W), wq.z, a[3]);
    a[0] = fmaf(el24<K0 + 3>(W), wq.w, a[0]); a[1] = fmaf(el24<K0 + 4>(W), wq.w, a[1]);
    a[2] = fmaf(el24<K0 + 5>(W), wq.w, a[2]); a[3] = fmaf(el24<K0 + 6>(W), wq.w, a[3]);
}

#define FQ2ALL(Q, W, g, a0, a1)                                                \
  do { fq2<0>(Q[0], W, g, a0, a1);  fq2<4>(Q[1], W, g, a0, a1);                \
       fq2<8>(Q[2], W, g, a0, a1);  fq2<12>(Q[3], W, g, a0, a1);               \
       fq2<16>(Q[4], W, g, a0, a1); } while (0)

// -------- Kernel 1: conv pipeline; phases A/B/C per-atom (R15 codegen),
// phase D paired across 2 atoms so conv2 weight reads are amortized 2x. ------
__global__ __launch_bounds__(256, 3) void atom_kernel(
    const float* __restrict__ oh_g,    // [M0,92]
    const float* __restrict__ env_g,   // [M0,55]
    const int*   __restrict__ idx_g,   // [M0] sorted
    const float* __restrict__ wA, const float* __restrict__ bA,  // [3*20],[3]
    const float* __restrict__ w1, const float* __restrict__ b1,  // [3*20],[3]
    const float* __restrict__ w2, const float* __restrict__ b2,  // [6*3*20],[6]
    float* __restrict__ sums,          // [NC,324]
    float* __restrict__ counts)        // [NC]
{
    __shared__ __align__(16) float w_lds[480];          // wA[0:60] w1[60:120] w2[120:480]
    __shared__ __align__(16) float s_total[4][280];     // single (reused per atom)
    __shared__ __align__(16) float s_one1[4][2][384];   // conv1 out, 2 pair-slots

    // XCD-chunk swizzle: consecutive (same-crystal) blocks share one XCD L2.
    const int bid = (blockIdx.x & 7) * 1024 + (blockIdx.x >> 3);

    const int wave = threadIdx.x >> 6;
    const int lane = threadIdx.x & 63;
    const int tid  = threadIdx.x;

    const unsigned w_b    = (unsigned)(size_t)w_lds;
    const unsigned wD_b   = w_b + 480u;                 // w2 bytes
    const unsigned tot_b  = (unsigned)(size_t)&s_total[wave][0];
    const unsigned oneA_b = (unsigned)(size_t)&s_one1[wave][0][0];
    const unsigned oneB_b = (unsigned)(size_t)&s_one1[wave][1][0];
    const unsigned lane8  = (unsigned)lane * 8u;
    const unsigned lane16 = (unsigned)lane * 16u;

    // ---- stage all conv weights into LDS once per block ----
    for (int i = tid; i < 360; i += 256) DSW32(w_b + (120u + (unsigned)i) * 4u, w2[i]);
    if (tid < 60)       DSW32(w_b + (unsigned)tid * 4u, wA[tid]);
    else if (tid < 120) DSW32(w_b + (unsigned)tid * 4u, w1[tid - 60]);
    __syncthreads();

    const int wbase = bid * 16 + wave * 4;

    float fa[6] = {0.f, 0.f, 0.f, 0.f, 0.f, 0.f};
    float cnt = 0.f;
    int cur = idx_g[wbase];

#define FLUSH()                                                                \
    do {                                                                       \
        if (lane < 54) {                                                       \
            float* dst = sums + (size_t)cur * FDIM + lane;                     \
            _Pragma("unroll")                                                  \
            for (int c2 = 0; c2 < 6; ++c2) {                                   \
                atomicAdd(dst + c2 * 54, fa[c2]);                              \
                fa[c2] = 0.f;                                                  \
            }                                                                  \
        }                                                                      \
        if (lane == 0) atomicAdd(&counts[cur], cnt);                           \
        cnt = 0.f;                                                             \
    } while (0)

    #pragma unroll
    for (int pp = 0; pp < 2; ++pp) {
        const int aA = wbase + 2 * pp;
        const int aB = aA + 1;
        const int cryA = idx_g[aA];
        const int cryB = idx_g[aB];

        // ---- Phases A,B,C per atom (R15 structure), output into slot s ----
        #pragma unroll
        for (int s = 0; s < 2; ++s) {
            const int atom = aA + s;
            const unsigned oneb = s ? oneB_b : oneA_b;   // oh scratch + conv1 out
            // Phase A
            if (lane < 46) {
                const float2 v = *reinterpret_cast<const float2*>(oh_g + (size_t)atom * 92 + 2 * lane);
                DSW64(oneb + lane8, v);
            }
            if (lane < 55) {
                DSW32(tot_b + (219u + (unsigned)lane) * 4u, env_g[(size_t)atom * 55 + lane]);
            }
            // Phase B: conva -> relu -> total[0..218]  (37 lanes x 2 pos)
            if (lane < 37) {
                float4 W[5]; float g;
                DSWIN21(W[0], W[1], W[2], W[3], W[4], g, oneb + lane8);
                const unsigned p2 = 2u * (unsigned)lane;
                #pragma unroll
                for (int c = 0; c < 3; ++c) {
                    float4 wq[5];
                    DSWQ5(wq, w_b + (unsigned)c * 80u);
                    float a0 = bA[c], a1 = a0;
                    FQ2ALL(wq, W, g, a0, a1);
                    const unsigned tb = tot_b + (73u * (unsigned)c + p2) * 4u;
                    DSW32(tb, fmaxf(a0, 0.f));
                    if (p2 + 1 < 73) DSW32(tb + 4u, fmaxf(a1, 0.f));
                }
            }
            // Phase C: conv1 + relu + maxpool2 -> one1[s][3][128]
            {
                float4 W[6];
                DSWIN24(W[0], W[1], W[2], W[3], W[4], W[5], tot_b + lane16);
                #pragma unroll
                for (int c = 0; c < 3; ++c) {
                    float4 wq[5];
                    DSWQ5(wq, w_b + 240u + (unsigned)c * 80u);
                    float a4[4] = {b1[c], b1[c], b1[c], b1[c]};
                    fq4<0>(wq[0], W, a4);  fq4<4>(wq[1], W, a4);  fq4<8>(wq[2], W, a4);
                    fq4<12>(wq[3], W, a4); fq4<16>(wq[4], W, a4);
                    float2 st;
                    st.x = fmaxf(fmaxf(a4[0], a4[1]), 0.f);
                    st.y = fmaxf(fmaxf(a4[2], a4[3]), 0.f);
                    DSW64(oneb + ((unsigned)c * 128u + 2u * (unsigned)lane) * 4u, st);
                }
            }
        }

        // ---- Phase D: conv2 weights ONCE per (ch,c2), both atoms' windows ----
        float accA0[6], accA1[6], accB0[6], accB1[6];
        #pragma unroll
        for (int c2 = 0; c2 < 6; ++c2) {
            accA0[c2] = b2[c2]; accA1[c2] = accA0[c2];
            accB0[c2] = accA0[c2]; accB1[c2] = accA0[c2];
        }
        #pragma unroll
        for (int ch = 0; ch < 3; ++ch) {
            float4 Wa[5]; float ga;
            float4 Wb[5]; float gb;
            DSWIN21(Wa[0], Wa[1], Wa[2], Wa[3], Wa[4], ga,
                    oneA_b + (unsigned)ch * 512u + lane8);
            DSWIN21(Wb[0], Wb[1], Wb[2], Wb[3], Wb[4], gb,
                    oneB_b + (unsigned)ch * 512u + lane8);
            #pragma unroll
            for (int c2 = 0; c2 < 6; ++c2) {
                float4 wq[5];
                DSWQ5(wq, wD_b + ((unsigned)c2 * 3u + (unsigned)ch) * 80u);
                FQ2ALL(wq, Wa, ga, accA0[c2], accA1[c2]);
                FQ2ALL(wq, Wb, gb, accB0[c2], accB1[c2]);
            }
        }

        // ---- accumulate per atom with crystal-change flush ----
        if (cryA != cur) { FLUSH(); cur = cryA; }
        if (lane < 54) {
            #pragma unroll
            for (int c2 = 0; c2 < 6; ++c2)
                fa[c2] += fmaxf(fmaxf(accA0[c2], accA1[c2]), 0.f);
        }
        cnt += 1.f;
        if (cryB != cur) { FLUSH(); cur = cryB; }
        if (lane < 54) {
            #pragma unroll
            for (int c2 = 0; c2 < 6; ++c2)
                fa[c2] += fmaxf(fmaxf(accB0[c2], accB1[c2]), 0.f);
        }
        cnt += 1.f;
    }

    FLUSH();
#undef FLUSH
}

// -------- Kernel 2: per-crystal mean+relu, 324->32 softplus, 32->1 ----------
__global__ __launch_bounds__(64) void head_kernel(
    const float* __restrict__ sums, const float* __restrict__ counts,
    const float* __restrict__ lin_w, const float* __restrict__ lin_b,
    const float* __restrict__ lin1_w, const float* __restrict__ lin1_b,
    float* __restrict__ out)
{
    __shared__ float p[FDIM];
    const int c = blockIdx.x;
    const int lane = threadIdx.x;
    const float inv = 1.0f / fmaxf(counts[c], 1.0f);
    for (int i = lane; i < FDIM; i += 64)
        p[i] = fmaxf(sums[(size_t)c * FDIM + i] * inv, 0.f);
    __syncthreads();

    float r = 0.f;
    if (lane < 32) {
        float acc = lin_b[lane];
        const float* wrow = lin_w + lane * FDIM;
        #pragma unroll 4
        for (int i = 0; i < FDIM; ++i) acc = fmaf(p[i], wrow[i], acc);
        const float sp = (acc > 0.f) ? acc + log1pf(expf(-acc)) : log1pf(expf(acc));
        r = sp * lin1_w[lane];
    }
    #pragma unroll
    for (int off = 16; off; off >>= 1) r += __shfl_down(r, off);
    if (lane == 0) out[c] = r + lin1_b[0];
}

extern "C" void kernel_launch(void* const* d_in, const int* in_sizes, int n_in,
                              void* d_out, int out_size, void* d_ws, size_t ws_size,
                              hipStream_t stream) {
    (void)in_sizes; (void)n_in; (void)out_size; (void)ws_size;
    const float* oh    = (const float*)d_in[0];
    const float* env   = (const float*)d_in[1];
    const int*   idx   = (const int*)  d_in[2];
    // d_in[3] = num_segments (constant 4096)
    const float* wA    = (const float*)d_in[4];
    const float* bA    = (const float*)d_in[5];
    const float* w1    = (const float*)d_in[6];
    const float* b1    = (const float*)d_in[7];
    const float* w2    = (const float*)d_in[8];
    const float* b2    = (const float*)d_in[9];
    const float* lin_w = (const float*)d_in[10];
    const float* lin_b = (const float*)d_in[11];
    const float* lin1_w= (const float*)d_in[12];
    const float* lin1_b= (const float*)d_in[13];

    float* sums   = (float*)d_ws;             // [NC*FDIM]
    float* counts = sums + (size_t)NC * FDIM; // [NC]

    hipMemsetAsync(d_ws, 0, ((size_t)NC * FDIM + NC) * sizeof(float), stream);

    // 8192 blocks x 4 waves x 4 atoms = M0
    atom_kernel<<<M0 / 16, 256, 0, stream>>>(oh, env, idx, wA, bA, w1, b1,
                                             w2, b2, sums, counts);
    head_kernel<<<NC, 64, 0, stream>>>(sums, counts, lin_w, lin_b, lin1_w, lin1_b,
                                       (float*)d_out);
}

// Round 20
// 291.250 us; speedup vs baseline: 13.5388x; 12.7113x over previous
//
#include <hip/hip_runtime.h>
#include <math.h>

#define M0 131072
#define NC 4096
#define FDIM 324   // 6*54
#define APW 4      // atoms per wave (sorted idx -> mostly same crystal)

typedef __attribute__((ext_vector_type(16))) float f32x16;
typedef __attribute__((ext_vector_type(4)))  float f32x4s;

// ---- DS window reads, wait INSIDE block (proven R12/R15 form) ----
#define DSWIN21(w0, w1, w2, w3, w4, g, addr)                                   \
  asm volatile("ds_read2_b64 %0, %6 offset0:0 offset1:1\n\t"                   \
               "ds_read2_b64 %1, %6 offset0:2 offset1:3\n\t"                   \
               "ds_read2_b64 %2, %6 offset0:4 offset1:5\n\t"                   \
               "ds_read2_b64 %3, %6 offset0:6 offset1:7\n\t"                   \
               "ds_read2_b64 %4, %6 offset0:8 offset1:9\n\t"                   \
               "ds_read_b32 %5, %6 offset:80\n\t"                              \
               "s_waitcnt lgkmcnt(0)"                                          \
               : "=v"(w0), "=v"(w1), "=v"(w2), "=v"(w3), "=v"(w4), "=v"(g)     \
               : "v"(addr))

#define DSWIN24(w0, w1, w2, w3, w4, w5, addr)                                  \
  asm volatile("ds_read_b128 %0, %6 offset:0\n\t"                              \
               "ds_read_b128 %1, %6 offset:16\n\t"                             \
               "ds_read_b128 %2, %6 offset:32\n\t"                             \
               "ds_read_b128 %3, %6 offset:48\n\t"                             \
               "ds_read_b128 %4, %6 offset:64\n\t"                             \
               "ds_read_b128 %5, %6 offset:80\n\t"                             \
               "s_waitcnt lgkmcnt(0)"                                          \
               : "=v"(w0), "=v"(w1), "=v"(w2), "=v"(w3), "=v"(w4), "=v"(w5)    \
               : "v"(addr))

#define DSW64(addr, val)  asm volatile("ds_write_b64 %0, %1" :: "v"(addr), "v"(val))
#define DSW32(addr, val)  asm volatile("ds_write_b32 %0, %1" :: "v"(addr), "v"(val))

// ---- 20 wave-uniform weights -> SGPRs via scalar loads; wait in-block so all
// consumers (which read d16/d4) are dataflow-gated. Scalar pipe: zero DS/VALU.
#define SLDW20(d16, d4, ptr, O16, O4)                                          \
  asm volatile("s_load_dwordx16 %0, %2, %3\n\t"                                \
               "s_load_dwordx4 %1, %2, %4\n\t"                                 \
               "s_waitcnt lgkmcnt(0)"                                          \
               : "=&s"(d16), "=&s"(d4)                                         \
               : "s"(ptr), "n"(O16), "n"(O4))

// ---- compile-time window element accessors ----
template<int J>
__device__ __forceinline__ float el21(const float4 (&W)[5], float g) {
    if constexpr (J >= 20) return g;
    else {
        constexpr int q = J >> 2, r = J & 3;
        if constexpr (r == 0) return W[q].x;
        else if constexpr (r == 1) return W[q].y;
        else if constexpr (r == 2) return W[q].z;
        else return W[q].w;
    }
}
template<int J>
__device__ __forceinline__ float el24(const float4 (&W)[6]) {
    constexpr int q = J >> 2, r = J & 3;
    if constexpr (r == 0) return W[q].x;
    else if constexpr (r == 1) return W[q].y;
    else if constexpr (r == 2) return W[q].z;
    else return W[q].w;
}

// one k-step, 2 pooled positions (weight in SGPR, window in VGPR)
template<int K>
__device__ __forceinline__ void sfq2(const float wk, const float4 (&W)[5], float g,
                                     float& a0, float& a1) {
    a0 = fmaf(el21<K>(W, g),     wk, a0);
    a1 = fmaf(el21<K + 1>(W, g), wk, a1);
}
// one k-step, 4 unpooled positions
template<int K>
__device__ __forceinline__ void sfq4(const float wk, const float4 (&W)[6], float (&a)[4]) {
    a[0] = fmaf(el24<K>(W),     wk, a[0]);
    a[1] = fmaf(el24<K + 1>(W), wk, a[1]);
    a[2] = fmaf(el24<K + 2>(W), wk, a[2]);
    a[3] = fmaf(el24<K + 3>(W), wk, a[3]);
}

#define SFQ20_2(S16, S4, W, g, a0, a1) do {                                    \
  sfq2<0>(S16[0],W,g,a0,a1);  sfq2<1>(S16[1],W,g,a0,a1);                       \
  sfq2<2>(S16[2],W,g,a0,a1);  sfq2<3>(S16[3],W,g,a0,a1);                       \
  sfq2<4>(S16[4],W,g,a0,a1);  sfq2<5>(S16[5],W,g,a0,a1);                       \
  sfq2<6>(S16[6],W,g,a0,a1);  sfq2<7>(S16[7],W,g,a0,a1);                       \
  sfq2<8>(S16[8],W,g,a0,a1);  sfq2<9>(S16[9],W,g,a0,a1);                       \
  sfq2<10>(S16[10],W,g,a0,a1); sfq2<11>(S16[11],W,g,a0,a1);                    \
  sfq2<12>(S16[12],W,g,a0,a1); sfq2<13>(S16[13],W,g,a0,a1);                    \
  sfq2<14>(S16[14],W,g,a0,a1); sfq2<15>(S16[15],W,g,a0,a1);                    \
  sfq2<16>(S4[0],W,g,a0,a1);  sfq2<17>(S4[1],W,g,a0,a1);                       \
  sfq2<18>(S4[2],W,g,a0,a1);  sfq2<19>(S4[3],W,g,a0,a1); } while (0)

#define SFQ20_4(S16, S4, W, a) do {                                            \
  sfq4<0>(S16[0],W,a);  sfq4<1>(S16[1],W,a);  sfq4<2>(S16[2],W,a);             \
  sfq4<3>(S16[3],W,a);  sfq4<4>(S16[4],W,a);  sfq4<5>(S16[5],W,a);             \
  sfq4<6>(S16[6],W,a);  sfq4<7>(S16[7],W,a);  sfq4<8>(S16[8],W,a);             \
  sfq4<9>(S16[9],W,a);  sfq4<10>(S16[10],W,a); sfq4<11>(S16[11],W,a);          \
  sfq4<12>(S16[12],W,a); sfq4<13>(S16[13],W,a); sfq4<14>(S16[14],W,a);         \
  sfq4<15>(S16[15],W,a); sfq4<16>(S4[0],W,a);  sfq4<17>(S4[1],W,a);            \
  sfq4<18>(S4[2],W,a);  sfq4<19>(S4[3],W,a); } while (0)

// Phase-D unit: weights for (c2,ch) = IDX from SGPRs, 40 FMAs.
template<int IDX>
__device__ __forceinline__ void d_one(const float* __restrict__ w2p,
                                      const float4 (&W)[5], float g,
                                      float& a0, float& a1) {
    f32x16 s16; f32x4s s4;
    SLDW20(s16, s4, w2p, IDX * 80, IDX * 80 + 64);
    SFQ20_2(s16, s4, W, g, a0, a1);
}

// -------- Kernel 1: per-atom conv pipeline, weights via scalar loads --------
__global__ __launch_bounds__(256, 8) void atom_kernel(
    const float* __restrict__ oh_g,    // [M0,92]
    const float* __restrict__ env_g,   // [M0,55]
    const int*   __restrict__ idx_g,   // [M0] sorted
    const float* __restrict__ wA, const float* __restrict__ bA,  // [3*20],[3]
    const float* __restrict__ w1, const float* __restrict__ b1,  // [3*20],[3]
    const float* __restrict__ w2, const float* __restrict__ b2,  // [6*3*20],[6]
    float* __restrict__ sums,          // [NC,324]
    float* __restrict__ counts)        // [NC]
{
    __shared__ __align__(16) float s_total[4][280];   // concat(atom[219], env[55])
    __shared__ __align__(16) float s_one1[4][384];    // conv1 pooled [3][128]; first 92 = oh scratch

    // XCD-chunk swizzle: consecutive (same-crystal) blocks share one XCD L2.
    const int bid = (blockIdx.x & 7) * 1024 + (blockIdx.x >> 3);

    const int wave = threadIdx.x >> 6;
    const int lane = threadIdx.x & 63;

    const unsigned tot_b = (unsigned)(size_t)&s_total[wave][0];
    const unsigned one_b = (unsigned)(size_t)&s_one1[wave][0];
    const unsigned lane8  = (unsigned)lane * 8u;
    const unsigned lane16 = (unsigned)lane * 16u;

    const int wbase = (bid * 4 + wave) * APW;

    float fa[6] = {0.f, 0.f, 0.f, 0.f, 0.f, 0.f};
    float cnt = 0.f;
    int cur = idx_g[wbase];

    for (int it = 0; it < APW; ++it) {
        const int atom = wbase + it;
        const int cry = idx_g[atom];                  // wave-uniform
        if (cry != cur) {                             // uniform branch: flush
            if (lane < 54) {
                float* dst = sums + (size_t)cur * FDIM + lane;
                #pragma unroll
                for (int c2 = 0; c2 < 6; ++c2) {
                    atomicAdd(dst + c2 * 54, fa[c2]);
                    fa[c2] = 0.f;
                }
            }
            if (lane == 0) atomicAdd(&counts[cur], cnt);
            cnt = 0.f;
            cur = cry;
        }

        // ---- Phase A: one-hot (92) + env (55) into LDS ----
        if (lane < 46) {
            const float2 v = *reinterpret_cast<const float2*>(oh_g + (size_t)atom * 92 + 2 * lane);
            DSW64(one_b + lane8, v);
        }
        if (lane < 55) {
            DSW32(tot_b + (219u + (unsigned)lane) * 4u, env_g[(size_t)atom * 55 + lane]);
        }

        // ---- Phase B: conva -> relu -> total[0..218]  (37 lanes x 2 pos) ----
        if (lane < 37) {
            float4 W[5]; float g;
            DSWIN21(W[0], W[1], W[2], W[3], W[4], g, one_b + lane8);
            const unsigned p2 = 2u * (unsigned)lane;
            {
                f32x16 s16; f32x4s s4;
                SLDW20(s16, s4, wA, 0, 64);
                float a0 = bA[0], a1 = a0;
                SFQ20_2(s16, s4, W, g, a0, a1);
                DSW32(tot_b + p2 * 4u, fmaxf(a0, 0.f));
                if (p2 + 1 < 73) DSW32(tot_b + (p2 + 1) * 4u, fmaxf(a1, 0.f));
            }
            {
                f32x16 s16; f32x4s s4;
                SLDW20(s16, s4, wA, 80, 144);
                float a0 = bA[1], a1 = a0;
                SFQ20_2(s16, s4, W, g, a0, a1);
                DSW32(tot_b + (73u + p2) * 4u, fmaxf(a0, 0.f));
                if (p2 + 1 < 73) DSW32(tot_b + (74u + p2) * 4u, fmaxf(a1, 0.f));
            }
            {
                f32x16 s16; f32x4s s4;
                SLDW20(s16, s4, wA, 160, 224);
                float a0 = bA[2], a1 = a0;
                SFQ20_2(s16, s4, W, g, a0, a1);
                DSW32(tot_b + (146u + p2) * 4u, fmaxf(a0, 0.f));
                if (p2 + 1 < 73) DSW32(tot_b + (147u + p2) * 4u, fmaxf(a1, 0.f));
            }
        }

        // ---- Phase C: conv1 + relu + maxpool2 -> one1[3][128] (64 lanes x 4 pos) ----
        // lane q: unpooled 4q..4q+3 -> pooled {2q,2q+1}; q=63 garbage -> dead slot 127.
        {
            float4 W[6];
            DSWIN24(W[0], W[1], W[2], W[3], W[4], W[5], tot_b + lane16);
            {
                f32x16 s16; f32x4s s4;
                SLDW20(s16, s4, w1, 0, 64);
                float a4[4] = {b1[0], b1[0], b1[0], b1[0]};
                SFQ20_4(s16, s4, W, a4);
                float2 st;
                st.x = fmaxf(fmaxf(a4[0], a4[1]), 0.f);
                st.y = fmaxf(fmaxf(a4[2], a4[3]), 0.f);
                DSW64(one_b + (2u * (unsigned)lane) * 4u, st);
            }
            {
                f32x16 s16; f32x4s s4;
                SLDW20(s16, s4, w1, 80, 144);
                float a4[4] = {b1[1], b1[1], b1[1], b1[1]};
                SFQ20_4(s16, s4, W, a4);
                float2 st;
                st.x = fmaxf(fmaxf(a4[0], a4[1]), 0.f);
                st.y = fmaxf(fmaxf(a4[2], a4[3]), 0.f);
                DSW64(one_b + (128u + 2u * (unsigned)lane) * 4u, st);
            }
            {
                f32x16 s16; f32x4s s4;
                SLDW20(s16, s4, w1, 160, 224);
                float a4[4] = {b1[2], b1[2], b1[2], b1[2]};
                SFQ20_4(s16, s4, W, a4);
                float2 st;
                st.x = fmaxf(fmaxf(a4[0], a4[1]), 0.f);
                st.y = fmaxf(fmaxf(a4[2], a4[3]), 0.f);
                DSW64(one_b + (256u + 2u * (unsigned)lane) * 4u, st);
            }
        }

        // ---- Phase D: conv2 + relu + maxpool2 -> fa[6] (54 lanes); weights SGPR ----
        if (lane < 54) {
            float acc0[6], acc1[6];
            #pragma unroll
            for (int c2 = 0; c2 < 6; ++c2) { acc0[c2] = b2[c2]; acc1[c2] = acc0[c2]; }
            {   // ch = 0  (IDX = c2*3+ch)
                float4 W[5]; float g;
                DSWIN21(W[0], W[1], W[2], W[3], W[4], g, one_b + lane8);
                d_one<0>(w2, W, g, acc0[0], acc1[0]);
                d_one<3>(w2, W, g, acc0[1], acc1[1]);
                d_one<6>(w2, W, g, acc0[2], acc1[2]);
                d_one<9>(w2, W, g, acc0[3], acc1[3]);
                d_one<12>(w2, W, g, acc0[4], acc1[4]);
                d_one<15>(w2, W, g, acc0[5], acc1[5]);
            }
            {   // ch = 1
                float4 W[5]; float g;
                DSWIN21(W[0], W[1], W[2], W[3], W[4], g, one_b + 512u + lane8);
                d_one<1>(w2, W, g, acc0[0], acc1[0]);
                d_one<4>(w2, W, g, acc0[1], acc1[1]);
                d_one<7>(w2, W, g, acc0[2], acc1[2]);
                d_one<10>(w2, W, g, acc0[3], acc1[3]);
                d_one<13>(w2, W, g, acc0[4], acc1[4]);
                d_one<16>(w2, W, g, acc0[5], acc1[5]);
            }
            {   // ch = 2
                float4 W[5]; float g;
                DSWIN21(W[0], W[1], W[2], W[3], W[4], g, one_b + 1024u + lane8);
                d_one<2>(w2, W, g, acc0[0], acc1[0]);
                d_one<5>(w2, W, g, acc0[1], acc1[1]);
                d_one<8>(w2, W, g, acc0[2], acc1[2]);
                d_one<11>(w2, W, g, acc0[3], acc1[3]);
                d_one<14>(w2, W, g, acc0[4], acc1[4]);
                d_one<17>(w2, W, g, acc0[5], acc1[5]);
            }
            #pragma unroll
            for (int c2 = 0; c2 < 6; ++c2)
                fa[c2] += fmaxf(fmaxf(acc0[c2], acc1[c2]), 0.f);
        }
        cnt += 1.f;
    }

    // ---- final flush ----
    if (lane < 54) {
        float* dst = sums + (size_t)cur * FDIM + lane;
        #pragma unroll
        for (int c2 = 0; c2 < 6; ++c2) atomicAdd(dst + c2 * 54, fa[c2]);
    }
    if (lane == 0) atomicAdd(&counts[cur], cnt);
}

// -------- Kernel 2: per-crystal mean+relu, 324->32 softplus, 32->1 ----------
__global__ __launch_bounds__(64) void head_kernel(
    const float* __restrict__ sums, const float* __restrict__ counts,
    const float* __restrict__ lin_w, const float* __restrict__ lin_b,
    const float* __restrict__ lin1_w, const float* __restrict__ lin1_b,
    float* __restrict__ out)
{
    __shared__ float p[FDIM];
    const int c = blockIdx.x;
    const int lane = threadIdx.x;
    const float inv = 1.0f / fmaxf(counts[c], 1.0f);
    for (int i = lane; i < FDIM; i += 64)
        p[i] = fmaxf(sums[(size_t)c * FDIM + i] * inv, 0.f);
    __syncthreads();

    float r = 0.f;
    if (lane < 32) {
        float acc = lin_b[lane];
        const float* wrow = lin_w + lane * FDIM;
        #pragma unroll 4
        for (int i = 0; i < FDIM; ++i) acc = fmaf(p[i], wrow[i], acc);
        const float sp = (acc > 0.f) ? acc + log1pf(expf(-acc)) : log1pf(expf(acc));
        r = sp * lin1_w[lane];
    }
    #pragma unroll
    for (int off = 16; off; off >>= 1) r += __shfl_down(r, off);
    if (lane == 0) out[c] = r + lin1_b[0];
}

extern "C" void kernel_launch(void* const* d_in, const int* in_sizes, int n_in,
                              void* d_out, int out_size, void* d_ws, size_t ws_size,
                              hipStream_t stream) {
    (void)in_sizes; (void)n_in; (void)out_size; (void)ws_size;
    const float* oh    = (const float*)d_in[0];
    const float* env   = (const float*)d_in[1];
    const int*   idx   = (const int*)  d_in[2];
    // d_in[3] = num_segments (constant 4096)
    const float* wA    = (const float*)d_in[4];
    const float* bA    = (const float*)d_in[5];
    const float* w1    = (const float*)d_in[6];
    const float* b1    = (const float*)d_in[7];
    const float* w2    = (const float*)d_in[8];
    const float* b2    = (const float*)d_in[9];
    const float* lin_w = (const float*)d_in[10];
    const float* lin_b = (const float*)d_in[11];
    const float* lin1_w= (const float*)d_in[12];
    const float* lin1_b= (const float*)d_in[13];

    float* sums   = (float*)d_ws;             // [NC*FDIM]
    float* counts = sums + (size_t)NC * FDIM; // [NC]

    hipMemsetAsync(d_ws, 0, ((size_t)NC * FDIM + NC) * sizeof(float), stream);

    // 8192 blocks x 4 waves x 4 atoms = M0
    atom_kernel<<<M0 / 16, 256, 0, stream>>>(oh, env, idx, wA, bA, w1, b1,
                                             w2, b2, sums, counts);
    head_kernel<<<NC, 64, 0, stream>>>(sums, counts, lin_w, lin_b, lin1_w, lin1_b,
                                       (float*)d_out);
}